// Round 8
// baseline (460.400 us; speedup 1.0000x reference)
//
#include <hip/hip_runtime.h>
#include <math.h>

#define NHEADS 16
#define HDIM   64
#define HID    1024
#define BATCH  2
#define SEQ    2048
#define NX (BATCH*SEQ*HID)       // 4194304
#define NW (HID*HID)             // 1048576

typedef unsigned short u16;
typedef __attribute__((ext_vector_type(8))) short  bf16x8;   // 8 bf16 = 4 VGPR
typedef __attribute__((ext_vector_type(8))) unsigned short u16x8;
typedef __attribute__((ext_vector_type(4))) float  f32x4;

// ---------------------------------------------------------------------------
// Fragment-tiled layout ("FT"): operand rows r, inner dim k. Subtile =
// 16 rows x 32 k. Element (r,k) lives at
//   ((r>>4)*KB + (k>>5))*512 + ((k>>3)&3)*128 + (r&15)*8 + (k&7)     [u16]
// A wave's MFMA fragment load (lane = quad*16+lx -> 16B) is 64 lanes x 16B
// CONTIGUOUS: perfectly coalesced global_load_dwordx4, no LDS round-trip.
// hi / lo planes are separate arrays (keeps lane stride 16B).
// ---------------------------------------------------------------------------

__device__ __forceinline__ void split8(const float* xf, bf16x8& hi, bf16x8& lo) {
#pragma unroll
    for (int j = 0; j < 8; j++) {
        unsigned u = __float_as_uint(xf[j]);
        hi[j] = (short)(u >> 16);
        float hf = __uint_as_float(u & 0xFFFF0000u);
        lo[j] = (short)(__float_as_uint(xf[j] - hf) >> 16);
    }
}
__device__ __forceinline__ void split1(float v, u16& h, u16& l) {
    unsigned u = __float_as_uint(v);
    h = (u16)(u >> 16);
    l = (u16)(__float_as_uint(v - __uint_as_float(u & 0xFFFF0000u)) >> 16);
}

// ---------------------------------------------------------------------------
// RoPE tables
// ---------------------------------------------------------------------------
__global__ void rope_tables_kernel(float* __restrict__ ct, float* __restrict__ st) {
    int idx = blockIdx.x * 256 + threadIdx.x;
    if (idx >= SEQ * HDIM) return;
    int s  = idx >> 6;
    int dh = idx & 63;
    int i  = dh & 31;
    float inv = exp2f(-(float)i * (13.28771237954945f / 32.0f));  // log2(10000)/32
    float fr  = (float)s * inv;
    ct[idx] = cosf(fr);
    st[idx] = sinf(fr);
}

// ---------------------------------------------------------------------------
// Pre-pass: split X and W0/1/2 -> bf16 hi/lo planes, FRAG-TILED (KB=32).
// One wave per 16x32 subtile: reads 16 rows x 128B, writes 2 x 1KB contiguous.
// ---------------------------------------------------------------------------
#define NSUBX 8192               // X subtiles: 256 row-blocks x 32 k-blocks
#define NSUBW 6144               // W subtiles: 3 x (64 x 32)
__global__ void split_kernel(const float* __restrict__ X,
                             const float* __restrict__ W0,
                             const float* __restrict__ W1,
                             const float* __restrict__ W2,
                             u16* __restrict__ Xhi, u16* __restrict__ Xlo,
                             u16* __restrict__ Whi, u16* __restrict__ Wlo)
{
    const int wid  = (blockIdx.x * 256 + threadIdx.x) >> 6;
    const int lane = threadIdx.x & 63;
    if (wid >= NSUBX + NSUBW) return;
    const float* src; u16 *dh, *dl; int id;
    if (wid < NSUBX) { src = X; dh = Xhi; dl = Xlo; id = wid; }
    else {
        int r  = wid - NSUBX;
        int wi = r >> 11;                 // 2048 subtiles per W
        id = r & 2047;
        src = (wi == 0) ? W0 : ((wi == 1) ? W1 : W2);
        dh = Whi + (size_t)wi * NW;
        dl = Wlo + (size_t)wi * NW;
    }
    const int rb = id >> 5, kb = id & 31;
    const int lx = lane & 15, quad = lane >> 4;
    const float* s = src + (size_t)(rb * 16 + lx) * HID + kb * 32 + quad * 8;
    float xf[8];
    *(float4*)&xf[0] = *(const float4*)s;
    *(float4*)&xf[4] = *(const float4*)(s + 4);
    bf16x8 hi, lo;
    split8(xf, hi, lo);
    const size_t fo = (size_t)id * 512 + quad * 128 + lx * 8;
    *(bf16x8*)(dh + fo) = hi;
    *(bf16x8*)(dl + fo) = lo;
}

// ---------------------------------------------------------------------------
// MFMA QKV GEMM (unchanged from R7): no LDS / no barriers in K-loop,
// frag-tiled global operands, register double-buffer.
// ---------------------------------------------------------------------------
__global__ __launch_bounds__(256, 2) void qkv_mfma_kernel(
    const u16* __restrict__ Xhi, const u16* __restrict__ Xlo,
    const u16* __restrict__ Whi, const u16* __restrict__ Wlo,
    const float* __restrict__ ct, const float* __restrict__ st,
    u16* __restrict__ Qhi, u16* __restrict__ Qlo,
    u16* __restrict__ Khi, u16* __restrict__ Klo,
    u16* __restrict__ Vhi, u16* __restrict__ Vlo)
{
    __shared__ unsigned vtr[64][129];   // proj-2 transpose buffer only

    const int t    = threadIdx.x;
    const int lane = t & 63;
    const int w    = t >> 6;
    const int lx   = lane & 15;
    const int quad = lane >> 4;
    const int proj = blockIdx.z;
    const int n0   = blockIdx.x * 128;
    const int m0   = blockIdx.y * 128;

    const u16* __restrict__ Wph = Whi + (size_t)proj * NW;
    const u16* __restrict__ Wpl = Wlo + (size_t)proj * NW;

    const int am = (w & 1) * 64;
    const int bn = (w >> 1) * 64;
    const int lp = quad * 128 + lx * 8;

    const u16 *pAh[4], *pAl[4], *pBh[4], *pBl[4];
#pragma unroll
    for (int i = 0; i < 4; i++) {
        const size_t o = ((size_t)(((m0 + am) >> 4) + i) * 32) * 512 + lp;
        pAh[i] = Xhi + o; pAl[i] = Xlo + o;
    }
#pragma unroll
    for (int j = 0; j < 4; j++) {
        const size_t o = ((size_t)(((n0 + bn) >> 4) + j) * 32) * 512 + lp;
        pBh[j] = Wph + o; pBl[j] = Wpl + o;
    }

    f32x4 acc[4][4];
#pragma unroll
    for (int i = 0; i < 4; i++)
#pragma unroll
        for (int j = 0; j < 4; j++) acc[i][j] = (f32x4){0.f, 0.f, 0.f, 0.f};

    bf16x8 cah[4], cal[4], cbh[4], cbl[4];
#pragma unroll
    for (int i = 0; i < 4; i++) { cah[i] = *(const bf16x8*)(pAh[i]); cal[i] = *(const bf16x8*)(pAl[i]); }
#pragma unroll
    for (int j = 0; j < 4; j++) { cbh[j] = *(const bf16x8*)(pBh[j]); cbl[j] = *(const bf16x8*)(pBl[j]); }

#pragma unroll 1
    for (int kt = 0; kt < HID; kt += 32) {
        const int ko = (kt + 32 < HID) ? ((kt + 32) >> 5) * 512 : 0;
        bf16x8 nah[4], nal[4], nbh[4], nbl[4];
#pragma unroll
        for (int i = 0; i < 4; i++) { nah[i] = *(const bf16x8*)(pAh[i] + ko); nal[i] = *(const bf16x8*)(pAl[i] + ko); }
#pragma unroll
        for (int j = 0; j < 4; j++) { nbh[j] = *(const bf16x8*)(pBh[j] + ko); nbl[j] = *(const bf16x8*)(pBl[j] + ko); }

#pragma unroll
        for (int j = 0; j < 4; j++)
#pragma unroll
            for (int i = 0; i < 4; i++) {
                acc[i][j] = __builtin_amdgcn_mfma_f32_16x16x32_bf16(cah[i], cbh[j], acc[i][j], 0, 0, 0);
                acc[i][j] = __builtin_amdgcn_mfma_f32_16x16x32_bf16(cal[i], cbh[j], acc[i][j], 0, 0, 0);
                acc[i][j] = __builtin_amdgcn_mfma_f32_16x16x32_bf16(cah[i], cbl[j], acc[i][j], 0, 0, 0);
            }
#pragma unroll
        for (int i = 0; i < 4; i++) { cah[i] = nah[i]; cal[i] = nal[i]; }
#pragma unroll
        for (int j = 0; j < 4; j++) { cbh[j] = nbh[j]; cbl[j] = nbl[j]; }
    }

    // ---- epilogue ----
    const int b      = m0 >> 11;
    const int head   = (n0 >> 6) + (w >> 1);
    const int m_base = m0 + am;

    if (proj < 2) {
#pragma unroll
        for (int i = 0; i < 4; i++) {
#pragma unroll
            for (int r = 0; r < 4; r++) {
                const int s = (m_base + i * 16 + quad * 4 + r) & 2047;
                const float* ctr = ct + s * HDIM;
                const float* str = st + s * HDIM;
                float nv[4];
#pragma unroll
                for (int j = 0; j < 4; j++) {
                    const int dh = j * 16 + lx;
                    const float c  = ctr[dh];
                    const float sn = str[dh];
                    const float x  = acc[i][j][r];
                    const float p  = acc[i][j ^ 2][r];
                    nv[j] = (j < 2) ? (x * c - p * sn) : (x * c + p * sn);
                }
#pragma unroll
                for (int j = 0; j < 4; j++) acc[i][j][r] = nv[j];
            }
        }
        u16* dh_ = (proj == 0) ? Qhi : Khi;
        u16* dl_ = (proj == 0) ? Qlo : Klo;
        const size_t obase = (size_t)(b * NHEADS + head) * SEQ * HDIM;
#pragma unroll
        for (int i = 0; i < 4; i++)
#pragma unroll
            for (int r = 0; r < 4; r++) {
                const int s   = (m_base + i * 16 + quad * 4 + r) & 2047;
                const int rb  = s >> 4;
                const int lxq = s & 15;
#pragma unroll
                for (int j = 0; j < 4; j++) {
                    const size_t fo = obase + ((size_t)rb * 2 + (j >> 1)) * 512
                                    + (size_t)((j & 1) * 2 + (lx >> 3)) * 128
                                    + (size_t)lxq * 8 + (lx & 7);
                    u16 hh, ll;
                    split1(acc[i][j][r], hh, ll);
                    dh_[fo] = hh;
                    dl_[fo] = ll;
                }
            }
    } else {
#pragma unroll 1
        for (int pass = 0; pass < 2; pass++) {
            __syncthreads();
            if ((w & 1) == pass) {
#pragma unroll
                for (int i = 0; i < 4; i++)
#pragma unroll
                    for (int j = 0; j < 4; j++)
#pragma unroll
                        for (int r = 0; r < 4; r++) {
                            const int ml = i * 16 + quad * 4 + r;
                            const int nl = bn + j * 16 + lx;
                            const float v = acc[i][j][r];
                            unsigned u  = __float_as_uint(v);
                            unsigned hi = u & 0xFFFF0000u;
                            unsigned lo = __float_as_uint(v - __uint_as_float(hi)) >> 16;
                            vtr[ml][nl] = hi | lo;
                        }
            }
            __syncthreads();
            {
                const int d      = t >> 1;
                const int sh     = (t & 1) * 32;
                const int headv  = (n0 >> 6) + (d >> 6);
                const int dd     = d & 63;
                const size_t vbase = (size_t)(b * NHEADS + headv) * SEQ * HDIM;
                const int s0base = (m0 & 2047) + pass * 64 + sh;
#pragma unroll
                for (int k = 0; k < 4; k++) {
                    const int s0 = s0base + k * 8;
                    u16x8 hv, lv;
#pragma unroll
                    for (int e = 0; e < 8; e++) {
                        unsigned u = vtr[sh + k * 8 + e][d];
                        hv[e] = (u16)(u >> 16);
                        lv[e] = (u16)(u & 0xFFFFu);
                    }
                    const size_t fo = vbase + ((size_t)(dd >> 4) * 64 + (s0 >> 5)) * 512
                                    + (size_t)((s0 >> 3) & 3) * 128 + (size_t)(dd & 15) * 8;
                    *(u16x8*)(Vhi + fo) = hv;
                    *(u16x8*)(Vlo + fo) = lv;
                }
            }
        }
    }
}

// ---------------------------------------------------------------------------
// Flash attention: 512 threads = 8 waves x 16 q (grid-parallelism fix:
// 4 waves/SIMD vs R7's 2). No LDS for K/V (frag-tiled global), no barriers
// in the tile loop; P stays in per-wave LDS region (wave-internal).
// ---------------------------------------------------------------------------
__global__ __launch_bounds__(512, 2) void attn_kernel(
    const u16* __restrict__ Qhi, const u16* __restrict__ Qlo,
    const u16* __restrict__ Khi, const u16* __restrict__ Klo,
    const u16* __restrict__ Vhi, const u16* __restrict__ Vlo,
    float* __restrict__ OUT)
{
    __shared__ float PS[8][16][68];   // per-wave P; flat = [128][68] for store

    const int t    = threadIdx.x;
    const int lane = t & 63;
    const int w    = t >> 6;          // 0..7
    const int lx   = lane & 15;
    const int quad = lane >> 4;

    const int q0 = blockIdx.x * 128;
    const int h  = blockIdx.y;
    const int b  = blockIdx.z;
    const size_t base = (size_t)(b * NHEADS + h) * SEQ * HDIM;
    const int lp = quad * 128 + lx * 8;

    // Q fragments: wave's 16 q rows = row-block (q0>>4)+w
    bf16x8 qh[2], ql[2];
#pragma unroll
    for (int ks = 0; ks < 2; ks++) {
        const size_t fo = base + ((size_t)((q0 >> 4) + w) * 2 + ks) * 512 + lp;
        qh[ks] = *(const bf16x8*)(Qhi + fo);
        ql[ks] = *(const bf16x8*)(Qlo + fo);
    }

    f32x4 O[4];
    float l_part[4];
#pragma unroll
    for (int dt = 0; dt < 4; dt++) O[dt] = (f32x4){0.f,0.f,0.f,0.f};
#pragma unroll
    for (int r = 0; r < 4; r++) l_part[r] = 0.f;

#pragma unroll 1
    for (int kt = 0; kt < SEQ; kt += 64) {
        // ---- K fragments ----
        bf16x8 kh[2][4], kl[2][4];
#pragma unroll
        for (int c = 0; c < 4; c++)
#pragma unroll
            for (int ks = 0; ks < 2; ks++) {
                const size_t fo = base + ((size_t)((kt >> 4) + c) * 2 + ks) * 512 + lp;
                kh[ks][c] = *(const bf16x8*)(Khi + fo);
                kl[ks][c] = *(const bf16x8*)(Klo + fo);
            }

        // ---- scores + exp -> PS ----
#pragma unroll
        for (int c = 0; c < 4; c++) {
            f32x4 acc = (f32x4){0.f,0.f,0.f,0.f};
#pragma unroll
            for (int ks = 0; ks < 2; ks++) {
                acc = __builtin_amdgcn_mfma_f32_16x16x32_bf16(qh[ks], kh[ks][c], acc, 0, 0, 0);
                acc = __builtin_amdgcn_mfma_f32_16x16x32_bf16(ql[ks], kh[ks][c], acc, 0, 0, 0);
                acc = __builtin_amdgcn_mfma_f32_16x16x32_bf16(qh[ks], kl[ks][c], acc, 0, 0, 0);
            }
#pragma unroll
            for (int r = 0; r < 4; r++) {
                float p = exp2f(acc[r] * 0.18033688011112042f);   // exp(s/8)
                l_part[r] += p;
                PS[w][quad * 4 + r][c * 16 + lx] = p;
            }
        }

        // ---- V fragments ----
        bf16x8 vh[2][4], vl[2][4];
#pragma unroll
        for (int dt = 0; dt < 4; dt++)
#pragma unroll
            for (int ks2 = 0; ks2 < 2; ks2++) {
                const size_t fo = base + ((size_t)dt * 64 + (kt >> 5) + ks2) * 512 + lp;
                vh[ks2][dt] = *(const bf16x8*)(Vhi + fo);
                vl[ks2][dt] = *(const bf16x8*)(Vlo + fo);
            }

        // ---- PV ----
#pragma unroll
        for (int ks2 = 0; ks2 < 2; ks2++) {
            const float* ps = &PS[w][lx][ks2 * 32 + quad * 8];
            float pf[8];
            *(float4*)&pf[0] = *(const float4*)ps;
            *(float4*)&pf[4] = *(const float4*)(ps + 4);
            bf16x8 phi, plo;
            split8(pf, phi, plo);
#pragma unroll
            for (int dt = 0; dt < 4; dt++) {
                O[dt] = __builtin_amdgcn_mfma_f32_16x16x32_bf16(phi, vh[ks2][dt], O[dt], 0, 0, 0);
                O[dt] = __builtin_amdgcn_mfma_f32_16x16x32_bf16(plo, vh[ks2][dt], O[dt], 0, 0, 0);
                O[dt] = __builtin_amdgcn_mfma_f32_16x16x32_bf16(phi, vl[ks2][dt], O[dt], 0, 0, 0);
            }
        }
    }

    // ---- epilogue ----
    float linv[4];
#pragma unroll
    for (int r = 0; r < 4; r++) {
        float l = l_part[r];
        l += __shfl_xor(l, 1);
        l += __shfl_xor(l, 2);
        l += __shfl_xor(l, 4);
        l += __shfl_xor(l, 8);
        linv[r] = 1.f / l;
    }

    // write own-wave rows into PS (flat [128][68]), then cross-wave store
    float* Po = &PS[0][0][0];
#pragma unroll
    for (int dt = 0; dt < 4; dt++)
#pragma unroll
        for (int r = 0; r < 4; r++)
            Po[(size_t)(w * 16 + quad * 4 + r) * 68 + dt * 16 + lx] = O[dt][r] * linv[r];
    __syncthreads();
    {
        const int q   = t >> 2;        // 0..127
        const int seg = t & 3;         // 16-float segment
        const float* prow = Po + (size_t)q * 68 + seg * 16;
        float* dst = OUT + ((size_t)(b * SEQ + q0 + q)) * HID + h * HDIM + seg * 16;
#pragma unroll
        for (int e = 0; e < 4; e++)
            ((float4*)dst)[e] = ((const float4*)prow)[e];
    }
}

// ---------------------------------------------------------------------------
extern "C" void kernel_launch(void* const* d_in, const int* in_sizes, int n_in,
                              void* d_out, int out_size, void* d_ws, size_t ws_size,
                              hipStream_t stream)
{
    const float* X  = (const float*)d_in[0];
    const float* Wq = (const float*)d_in[1];
    const float* Wk = (const float*)d_in[2];
    const float* Wv = (const float*)d_in[3];
    float* out = (float*)d_out;

    const size_t qkv_elems = (size_t)BATCH * NHEADS * SEQ * HDIM;  // 4,194,304
    char* wsb = (char*)d_ws;
    float* ct  = (float*)wsb;                       // 0.5 MB
    float* st  = ct + (size_t)SEQ * HDIM;           // 0.5 MB
    u16* Xhi = (u16*)(st + (size_t)SEQ * HDIM);     // 8 MB
    u16* Xlo = Xhi + (size_t)NX;                    // 8 MB
    u16* Whi = Xlo + (size_t)NX;                    // 6 MB
    u16* Wlo = Whi + 3 * (size_t)NW;                // 6 MB
    u16* Qhi = Wlo + 3 * (size_t)NW;                // 8 MB
    u16* Qlo = Qhi + qkv_elems;                     // 8 MB
    u16* Khi = Qlo + qkv_elems;                     // 8 MB
    u16* Klo = Khi + qkv_elems;                     // 8 MB
    u16* Vhi = Klo + qkv_elems;                     // 8 MB
    u16* Vlo = Vhi + qkv_elems;                     // 8 MB   (total 77 MB)

    rope_tables_kernel<<<(SEQ * HDIM + 255) / 256, 256, 0, stream>>>(ct, st);

    split_kernel<<<(NSUBX + NSUBW) / 4, 256, 0, stream>>>(
        X, Wq, Wk, Wv, Xhi, Xlo, Whi, Wlo);

    qkv_mfma_kernel<<<dim3(HID / 128, (BATCH * SEQ) / 128, 3), 256, 0, stream>>>(
        Xhi, Xlo, Whi, Wlo, ct, st, Qhi, Qlo, Khi, Klo, Vhi, Vlo);

    attn_kernel<<<dim3(SEQ / 128, NHEADS, BATCH), 512, 0, stream>>>(
        Qhi, Qlo, Khi, Klo, Vhi, Vlo, out);
}

// Round 9
// 440.018 us; speedup vs baseline: 1.0463x; 1.0463x over previous
//
#include <hip/hip_runtime.h>
#include <math.h>

#define NHEADS 16
#define HDIM   64
#define HID    1024
#define BATCH  2
#define SEQ    2048
#define NBH    (BATCH*NHEADS)    // 32
#define NX (BATCH*SEQ*HID)       // 4194304
#define NW (HID*HID)             // 1048576

typedef unsigned short u16;
typedef __attribute__((ext_vector_type(8))) short  bf16x8;   // 8 bf16 = 4 VGPR
typedef __attribute__((ext_vector_type(8))) unsigned short u16x8;
typedef __attribute__((ext_vector_type(4))) float  f32x4;

// ---------------------------------------------------------------------------
// Fragment-tiled layout ("FT"): subtile = 16 rows x 32 k. Element (r,k) at
//   ((r>>4)*KB + (k>>5))*512 + ((k>>3)&3)*128 + (r&15)*8 + (k&7)   [u16]
// Wave fragment load (lane -> 16B) = 64 lanes x 16B contiguous; hi/lo planes
// are separate arrays.
// ---------------------------------------------------------------------------

__device__ __forceinline__ void split8(const float* xf, bf16x8& hi, bf16x8& lo) {
#pragma unroll
    for (int j = 0; j < 8; j++) {
        unsigned u = __float_as_uint(xf[j]);
        hi[j] = (short)(u >> 16);
        float hf = __uint_as_float(u & 0xFFFF0000u);
        lo[j] = (short)(__float_as_uint(xf[j] - hf) >> 16);
    }
}
__device__ __forceinline__ void split1(float v, u16& h, u16& l) {
    unsigned u = __float_as_uint(v);
    h = (u16)(u >> 16);
    l = (u16)(__float_as_uint(v - __uint_as_float(u & 0xFFFF0000u)) >> 16);
}

// ---------------------------------------------------------------------------
__global__ void rope_tables_kernel(float* __restrict__ ct, float* __restrict__ st) {
    int idx = blockIdx.x * 256 + threadIdx.x;
    if (idx >= SEQ * HDIM) return;
    int s  = idx >> 6;
    int dh = idx & 63;
    int i  = dh & 31;
    float inv = exp2f(-(float)i * (13.28771237954945f / 32.0f));  // log2(10000)/32
    float fr  = (float)s * inv;
    ct[idx] = cosf(fr);
    st[idx] = sinf(fr);
}

// ---------------------------------------------------------------------------
// Split X / W -> bf16 hi/lo planes, frag-tiled. One wave per 16x32 subtile.
// ---------------------------------------------------------------------------
#define NSUBX 8192
#define NSUBW 6144
__global__ void split_kernel(const float* __restrict__ X,
                             const float* __restrict__ W0,
                             const float* __restrict__ W1,
                             const float* __restrict__ W2,
                             u16* __restrict__ Xhi, u16* __restrict__ Xlo,
                             u16* __restrict__ Whi, u16* __restrict__ Wlo)
{
    const int wid  = (blockIdx.x * 256 + threadIdx.x) >> 6;
    const int lane = threadIdx.x & 63;
    if (wid >= NSUBX + NSUBW) return;
    const float* src; u16 *dh, *dl; int id;
    if (wid < NSUBX) { src = X; dh = Xhi; dl = Xlo; id = wid; }
    else {
        int r  = wid - NSUBX;
        int wi = r >> 11;
        id = r & 2047;
        src = (wi == 0) ? W0 : ((wi == 1) ? W1 : W2);
        dh = Whi + (size_t)wi * NW;
        dl = Wlo + (size_t)wi * NW;
    }
    const int rb = id >> 5, kb = id & 31;
    const int lx = lane & 15, quad = lane >> 4;
    const float* s = src + (size_t)(rb * 16 + lx) * HID + kb * 32 + quad * 8;
    float xf[8];
    *(float4*)&xf[0] = *(const float4*)s;
    *(float4*)&xf[4] = *(const float4*)(s + 4);
    bf16x8 hi, lo;
    split8(xf, hi, lo);
    const size_t fo = (size_t)id * 512 + quad * 128 + lx * 8;
    *(bf16x8*)(dh + fo) = hi;
    *(bf16x8*)(dl + fo) = lo;
}

// ---------------------------------------------------------------------------
// MFMA QKV GEMM (unchanged from R7): no LDS / no barriers in K-loop,
// frag-tiled global operands, register double-buffer.
// ---------------------------------------------------------------------------
__global__ __launch_bounds__(256, 2) void qkv_mfma_kernel(
    const u16* __restrict__ Xhi, const u16* __restrict__ Xlo,
    const u16* __restrict__ Whi, const u16* __restrict__ Wlo,
    const float* __restrict__ ct, const float* __restrict__ st,
    u16* __restrict__ Qhi, u16* __restrict__ Qlo,
    u16* __restrict__ Khi, u16* __restrict__ Klo,
    u16* __restrict__ Vhi, u16* __restrict__ Vlo)
{
    __shared__ unsigned vtr[64][129];

    const int t    = threadIdx.x;
    const int lane = t & 63;
    const int w    = t >> 6;
    const int lx   = lane & 15;
    const int quad = lane >> 4;
    const int proj = blockIdx.z;
    const int n0   = blockIdx.x * 128;
    const int m0   = blockIdx.y * 128;

    const u16* __restrict__ Wph = Whi + (size_t)proj * NW;
    const u16* __restrict__ Wpl = Wlo + (size_t)proj * NW;

    const int am = (w & 1) * 64;
    const int bn = (w >> 1) * 64;
    const int lp = quad * 128 + lx * 8;

    const u16 *pAh[4], *pAl[4], *pBh[4], *pBl[4];
#pragma unroll
    for (int i = 0; i < 4; i++) {
        const size_t o = ((size_t)(((m0 + am) >> 4) + i) * 32) * 512 + lp;
        pAh[i] = Xhi + o; pAl[i] = Xlo + o;
    }
#pragma unroll
    for (int j = 0; j < 4; j++) {
        const size_t o = ((size_t)(((n0 + bn) >> 4) + j) * 32) * 512 + lp;
        pBh[j] = Wph + o; pBl[j] = Wpl + o;
    }

    f32x4 acc[4][4];
#pragma unroll
    for (int i = 0; i < 4; i++)
#pragma unroll
        for (int j = 0; j < 4; j++) acc[i][j] = (f32x4){0.f, 0.f, 0.f, 0.f};

    bf16x8 cah[4], cal[4], cbh[4], cbl[4];
#pragma unroll
    for (int i = 0; i < 4; i++) { cah[i] = *(const bf16x8*)(pAh[i]); cal[i] = *(const bf16x8*)(pAl[i]); }
#pragma unroll
    for (int j = 0; j < 4; j++) { cbh[j] = *(const bf16x8*)(pBh[j]); cbl[j] = *(const bf16x8*)(pBl[j]); }

#pragma unroll 1
    for (int kt = 0; kt < HID; kt += 32) {
        const int ko = (kt + 32 < HID) ? ((kt + 32) >> 5) * 512 : 0;
        bf16x8 nah[4], nal[4], nbh[4], nbl[4];
#pragma unroll
        for (int i = 0; i < 4; i++) { nah[i] = *(const bf16x8*)(pAh[i] + ko); nal[i] = *(const bf16x8*)(pAl[i] + ko); }
#pragma unroll
        for (int j = 0; j < 4; j++) { nbh[j] = *(const bf16x8*)(pBh[j] + ko); nbl[j] = *(const bf16x8*)(pBl[j] + ko); }

#pragma unroll
        for (int j = 0; j < 4; j++)
#pragma unroll
            for (int i = 0; i < 4; i++) {
                acc[i][j] = __builtin_amdgcn_mfma_f32_16x16x32_bf16(cah[i], cbh[j], acc[i][j], 0, 0, 0);
                acc[i][j] = __builtin_amdgcn_mfma_f32_16x16x32_bf16(cal[i], cbh[j], acc[i][j], 0, 0, 0);
                acc[i][j] = __builtin_amdgcn_mfma_f32_16x16x32_bf16(cah[i], cbl[j], acc[i][j], 0, 0, 0);
            }
#pragma unroll
        for (int i = 0; i < 4; i++) { cah[i] = nah[i]; cal[i] = nal[i]; }
#pragma unroll
        for (int j = 0; j < 4; j++) { cbh[j] = nbh[j]; cbl[j] = nbl[j]; }
    }

    const int b      = m0 >> 11;
    const int head   = (n0 >> 6) + (w >> 1);
    const int m_base = m0 + am;

    if (proj < 2) {
#pragma unroll
        for (int i = 0; i < 4; i++) {
#pragma unroll
            for (int r = 0; r < 4; r++) {
                const int s = (m_base + i * 16 + quad * 4 + r) & 2047;
                const float* ctr = ct + s * HDIM;
                const float* str = st + s * HDIM;
                float nv[4];
#pragma unroll
                for (int j = 0; j < 4; j++) {
                    const int dh = j * 16 + lx;
                    const float c  = ctr[dh];
                    const float sn = str[dh];
                    const float x  = acc[i][j][r];
                    const float p  = acc[i][j ^ 2][r];
                    nv[j] = (j < 2) ? (x * c - p * sn) : (x * c + p * sn);
                }
#pragma unroll
                for (int j = 0; j < 4; j++) acc[i][j][r] = nv[j];
            }
        }
        u16* dh_ = (proj == 0) ? Qhi : Khi;
        u16* dl_ = (proj == 0) ? Qlo : Klo;
        const size_t obase = (size_t)(b * NHEADS + head) * SEQ * HDIM;
#pragma unroll
        for (int i = 0; i < 4; i++)
#pragma unroll
            for (int r = 0; r < 4; r++) {
                const int s   = (m_base + i * 16 + quad * 4 + r) & 2047;
                const int rb  = s >> 4;
                const int lxq = s & 15;
#pragma unroll
                for (int j = 0; j < 4; j++) {
                    const size_t fo = obase + ((size_t)rb * 2 + (j >> 1)) * 512
                                    + (size_t)((j & 1) * 2 + (lx >> 3)) * 128
                                    + (size_t)lxq * 8 + (lx & 7);
                    u16 hh, ll;
                    split1(acc[i][j][r], hh, ll);
                    dh_[fo] = hh;
                    dl_[fo] = ll;
                }
            }
    } else {
#pragma unroll 1
        for (int pass = 0; pass < 2; pass++) {
            __syncthreads();
            if ((w & 1) == pass) {
#pragma unroll
                for (int i = 0; i < 4; i++)
#pragma unroll
                    for (int j = 0; j < 4; j++)
#pragma unroll
                        for (int r = 0; r < 4; r++) {
                            const int ml = i * 16 + quad * 4 + r;
                            const int nl = bn + j * 16 + lx;
                            const float v = acc[i][j][r];
                            unsigned u  = __float_as_uint(v);
                            unsigned hi = u & 0xFFFF0000u;
                            unsigned lo = __float_as_uint(v - __uint_as_float(hi)) >> 16;
                            vtr[ml][nl] = hi | lo;
                        }
            }
            __syncthreads();
            {
                const int d      = t >> 1;
                const int sh     = (t & 1) * 32;
                const int headv  = (n0 >> 6) + (d >> 6);
                const int dd     = d & 63;
                const size_t vbase = (size_t)(b * NHEADS + headv) * SEQ * HDIM;
                const int s0base = (m0 & 2047) + pass * 64 + sh;
#pragma unroll
                for (int k = 0; k < 4; k++) {
                    const int s0 = s0base + k * 8;
                    u16x8 hv, lv;
#pragma unroll
                    for (int e = 0; e < 8; e++) {
                        unsigned u = vtr[sh + k * 8 + e][d];
                        hv[e] = (u16)(u >> 16);
                        lv[e] = (u16)(u & 0xFFFFu);
                    }
                    const size_t fo = vbase + ((size_t)(dd >> 4) * 64 + (s0 >> 5)) * 512
                                    + (size_t)((s0 >> 3) & 3) * 128 + (size_t)(dd & 15) * 8;
                    *(u16x8*)(Vhi + fo) = hv;
                    *(u16x8*)(Vlo + fo) = lv;
                }
            }
        }
    }
}

// ---------------------------------------------------------------------------
// Flash attention, R7 body (4 waves x 32 q), KV range from block args.
// mode 1: each block does half the keys, writes unnormalized O + l partials.
// mode 0: full KV, normalize, write output directly (fallback).
// ---------------------------------------------------------------------------
__global__ __launch_bounds__(256, 4) void attn_kernel(
    const u16* __restrict__ Qhi, const u16* __restrict__ Qlo,
    const u16* __restrict__ Khi, const u16* __restrict__ Klo,
    const u16* __restrict__ Vhi, const u16* __restrict__ Vlo,
    float* __restrict__ OUT, float* __restrict__ Opart,
    float* __restrict__ Lpart, int mode)
{
    __shared__ float PS[4][32][68];

    const int t    = threadIdx.x;
    const int lane = t & 63;
    const int w    = t >> 6;
    const int lx   = lane & 15;
    const int quad = lane >> 4;

    const int qt  = mode ? (blockIdx.x >> 1) : blockIdx.x;
    const int kvh = mode ? (blockIdx.x & 1) : 0;
    const int q0  = qt * 128;
    const int h   = blockIdx.y;
    const int b   = blockIdx.z;
    const int bh  = b * NHEADS + h;
    const size_t base = (size_t)bh * SEQ * HDIM;
    const int lp = quad * 128 + lx * 8;

    const int kt0 = mode ? kvh * (SEQ / 2) : 0;
    const int kt1 = mode ? kt0 + (SEQ / 2) : SEQ;

    bf16x8 qh[2][2], ql[2][2];
#pragma unroll
    for (int a = 0; a < 2; a++)
#pragma unroll
        for (int ks = 0; ks < 2; ks++) {
            const size_t fo = base + ((size_t)((q0 >> 4) + w * 2 + a) * 2 + ks) * 512 + lp;
            qh[a][ks] = *(const bf16x8*)(Qhi + fo);
            ql[a][ks] = *(const bf16x8*)(Qlo + fo);
        }

    f32x4 O[2][4];
    float l_part[2][4];
#pragma unroll
    for (int a = 0; a < 2; a++) {
#pragma unroll
        for (int dt = 0; dt < 4; dt++) O[a][dt] = (f32x4){0.f,0.f,0.f,0.f};
#pragma unroll
        for (int r = 0; r < 4; r++) l_part[a][r] = 0.f;
    }

#pragma unroll 1
    for (int kt = kt0; kt < kt1; kt += 64) {
        bf16x8 kh[2][4], kl[2][4];
#pragma unroll
        for (int c = 0; c < 4; c++)
#pragma unroll
            for (int ks = 0; ks < 2; ks++) {
                const size_t fo = base + ((size_t)((kt >> 4) + c) * 2 + ks) * 512 + lp;
                kh[ks][c] = *(const bf16x8*)(Khi + fo);
                kl[ks][c] = *(const bf16x8*)(Klo + fo);
            }

#pragma unroll
        for (int a = 0; a < 2; a++) {
#pragma unroll
            for (int c = 0; c < 4; c++) {
                f32x4 acc = (f32x4){0.f,0.f,0.f,0.f};
#pragma unroll
                for (int ks = 0; ks < 2; ks++) {
                    acc = __builtin_amdgcn_mfma_f32_16x16x32_bf16(qh[a][ks], kh[ks][c], acc, 0, 0, 0);
                    acc = __builtin_amdgcn_mfma_f32_16x16x32_bf16(ql[a][ks], kh[ks][c], acc, 0, 0, 0);
                    acc = __builtin_amdgcn_mfma_f32_16x16x32_bf16(qh[a][ks], kl[ks][c], acc, 0, 0, 0);
                }
#pragma unroll
                for (int r = 0; r < 4; r++) {
                    float p = exp2f(acc[r] * 0.18033688011112042f);   // exp(s/8)
                    l_part[a][r] += p;
                    PS[w][a * 16 + quad * 4 + r][c * 16 + lx] = p;
                }
            }
        }

        bf16x8 vh[2][4], vl[2][4];
#pragma unroll
        for (int dt = 0; dt < 4; dt++)
#pragma unroll
            for (int ks2 = 0; ks2 < 2; ks2++) {
                const size_t fo = base + ((size_t)dt * 64 + (kt >> 5) + ks2) * 512 + lp;
                vh[ks2][dt] = *(const bf16x8*)(Vhi + fo);
                vl[ks2][dt] = *(const bf16x8*)(Vlo + fo);
            }

#pragma unroll
        for (int a = 0; a < 2; a++) {
#pragma unroll
            for (int ks2 = 0; ks2 < 2; ks2++) {
                const float* ps = &PS[w][a * 16 + lx][ks2 * 32 + quad * 8];
                float pf[8];
                *(float4*)&pf[0] = *(const float4*)ps;
                *(float4*)&pf[4] = *(const float4*)(ps + 4);
                bf16x8 phi, plo;
                split8(pf, phi, plo);
#pragma unroll
                for (int dt = 0; dt < 4; dt++) {
                    O[a][dt] = __builtin_amdgcn_mfma_f32_16x16x32_bf16(phi, vh[ks2][dt], O[a][dt], 0, 0, 0);
                    O[a][dt] = __builtin_amdgcn_mfma_f32_16x16x32_bf16(plo, vh[ks2][dt], O[a][dt], 0, 0, 0);
                    O[a][dt] = __builtin_amdgcn_mfma_f32_16x16x32_bf16(phi, vl[ks2][dt], O[a][dt], 0, 0, 0);
                }
            }
        }
    }

    // ---- epilogue ----
    float lred[2][4];
#pragma unroll
    for (int a = 0; a < 2; a++)
#pragma unroll
        for (int r = 0; r < 4; r++) {
            float l = l_part[a][r];
            l += __shfl_xor(l, 1);
            l += __shfl_xor(l, 2);
            l += __shfl_xor(l, 4);
            l += __shfl_xor(l, 8);
            lred[a][r] = l;
        }

    if (mode && lx == 0) {
        const size_t lb = (size_t)kvh * NBH * SEQ + (size_t)bh * SEQ + q0 + w * 32;
#pragma unroll
        for (int a = 0; a < 2; a++)
#pragma unroll
            for (int r = 0; r < 4; r++)
                Lpart[lb + a * 16 + quad * 4 + r] = lred[a][r];
    }

    float* Po = &PS[0][0][0];   // reuse as [128][68]
    __syncthreads();
#pragma unroll
    for (int a = 0; a < 2; a++) {
#pragma unroll
        for (int r = 0; r < 4; r++) {
            const float sc = mode ? 1.f : (1.f / lred[a][r]);
#pragma unroll
            for (int dt = 0; dt < 4; dt++)
                Po[(size_t)(w * 32 + a * 16 + quad * 4 + r) * 68 + dt * 16 + lx] =
                    O[a][dt][r] * sc;
        }
    }
    __syncthreads();
    {
        const int q    = t >> 1;
        const int half = t & 1;
        const float* prow = Po + (size_t)q * 68 + half * 32;
        float* dst = mode
            ? (Opart + (((size_t)kvh * NBH + bh) * SEQ + (q0 + q)) * HDIM + half * 32)
            : (OUT + ((size_t)(b * SEQ + q0 + q)) * HID + h * HDIM + half * 32);
#pragma unroll
        for (int e = 0; e < 8; e++)
            ((float4*)dst)[e] = ((const float4*)prow)[e];
    }
}

// ---------------------------------------------------------------------------
// Combine: out = (O0 + O1) / (l0 + l1), layout [B][NH][S][D] -> [B][S][H]
// ---------------------------------------------------------------------------
__global__ void combine_kernel(const float* __restrict__ Opart,
                               const float* __restrict__ Lpart,
                               float* __restrict__ OUT)
{
    const long idx4 = ((long)blockIdx.x * 256 + threadIdx.x) * 4;   // over [bh][s][d]
    const int bh = (int)(idx4 >> 17);          // / (SEQ*HDIM)
    const int rem = (int)(idx4 & (SEQ * HDIM - 1));
    const int q = rem >> 6;
    const int d = rem & 63;
    float4 o0 = *(const float4*)(Opart + idx4);
    float4 o1 = *(const float4*)(Opart + (long)NBH * SEQ * HDIM + idx4);
    const float l0 = Lpart[(size_t)bh * SEQ + q];
    const float l1 = Lpart[(size_t)NBH * SEQ + (size_t)bh * SEQ + q];
    const float inv = 1.f / (l0 + l1);
    float4 o;
    o.x = (o0.x + o1.x) * inv;
    o.y = (o0.y + o1.y) * inv;
    o.z = (o0.z + o1.z) * inv;
    o.w = (o0.w + o1.w) * inv;
    const int b = bh >> 4, h = bh & 15;
    *(float4*)(OUT + ((size_t)(b * SEQ + q)) * HID + h * HDIM + d) = o;
}

// ---------------------------------------------------------------------------
extern "C" void kernel_launch(void* const* d_in, const int* in_sizes, int n_in,
                              void* d_out, int out_size, void* d_ws, size_t ws_size,
                              hipStream_t stream)
{
    const float* X  = (const float*)d_in[0];
    const float* Wq = (const float*)d_in[1];
    const float* Wk = (const float*)d_in[2];
    const float* Wv = (const float*)d_in[3];
    float* out = (float*)d_out;

    const size_t qkv_elems = (size_t)BATCH * NHEADS * SEQ * HDIM;  // 4,194,304
    char* wsb = (char*)d_ws;
    float* ct  = (float*)wsb;                       // 0.5 MB
    float* st  = ct + (size_t)SEQ * HDIM;           // 0.5 MB
    u16* Xhi = (u16*)(st + (size_t)SEQ * HDIM);     // 8 MB
    u16* Xlo = Xhi + (size_t)NX;                    // 8 MB
    u16* Whi = Xlo + (size_t)NX;                    // 6 MB
    u16* Wlo = Whi + 3 * (size_t)NW;                // 6 MB
    u16* Qhi = Wlo + 3 * (size_t)NW;                // 8 MB
    u16* Qlo = Qhi + qkv_elems;                     // 8 MB
    u16* Khi = Qlo + qkv_elems;                     // 8 MB
    u16* Klo = Khi + qkv_elems;                     // 8 MB
    u16* Vhi = Klo + qkv_elems;                     // 8 MB
    u16* Vlo = Vhi + qkv_elems;                     // 8 MB   (=77 MB)
    float* Opart = (float*)(Vlo + qkv_elems);       // 32 MB (2 halves)
    float* Lpart = Opart + 2 * qkv_elems;           // 0.5 MB
    const size_t need_split = (size_t)((char*)(Lpart + 2 * (size_t)NBH * SEQ) - wsb);

    rope_tables_kernel<<<(SEQ * HDIM + 255) / 256, 256, 0, stream>>>(ct, st);

    split_kernel<<<(NSUBX + NSUBW) / 4, 256, 0, stream>>>(
        X, Wq, Wk, Wv, Xhi, Xlo, Whi, Wlo);

    qkv_mfma_kernel<<<dim3(HID / 128, (BATCH * SEQ) / 128, 3), 256, 0, stream>>>(
        Xhi, Xlo, Whi, Wlo, ct, st, Qhi, Qlo, Khi, Klo, Vhi, Vlo);

    if (ws_size >= need_split) {
        attn_kernel<<<dim3((SEQ / 128) * 2, NHEADS, BATCH), 256, 0, stream>>>(
            Qhi, Qlo, Khi, Klo, Vhi, Vlo, out, Opart, Lpart, 1);
        combine_kernel<<<(int)((2 * qkv_elems / 4) / 256 / 2), 256, 0, stream>>>(
            Opart, Lpart, out);
    } else {
        attn_kernel<<<dim3(SEQ / 128, NHEADS, BATCH), 256, 0, stream>>>(
            Qhi, Qlo, Khi, Klo, Vhi, Vlo, out, Opart, Lpart, 0);
    }
}